// Round 1
// baseline (7734.811 us; speedup 1.0000x reference)
//
#include <hip/hip_runtime.h>
#include <hip/hip_bf16.h>
#include <stdint.h>

#define NB 64
#define TT 1024
#define DD 512
#define HH 512

typedef short bf16x8 __attribute__((ext_vector_type(8)));
typedef float f32x4 __attribute__((ext_vector_type(4)));
typedef unsigned int u32;
typedef unsigned short u16;

// ---- workspace layout (bytes) ----
#define SZ_WPACK  (32ull*4*4*8*1024)          // 4 MiB: B-fragments, packed per (wg,wave,n,kk)
#define OFF_WPACK 0ull
#define OFF_XS    (OFF_WPACK + SZ_WPACK)       // 64 MiB: per-t swizzled bf16 A-images of x
#define SZ_XS     (1024ull*65536)
#define OFF_HBUF  (OFF_XS + SZ_XS)             // 128 KiB: double-buffered swizzled bf16 h
#define SZ_HBUF   (2ull*65536)
#define OFF_FLAGS (OFF_HBUF + SZ_HBUF)         // 4 KiB: 32 flags, 128B apart

__device__ __forceinline__ u16 f2bf(float f){
  u32 u = __builtin_bit_cast(u32, f);
  u32 r = (u + 0x7fffu + ((u >> 16) & 1u)) >> 16;   // RNE
  return (u16)r;
}

// ---- prep: flags = -1 (must run every launch; harness doesn't re-poison) ----
__global__ void k_init_flags(int* flags){
  if (threadIdx.x < 32) flags[threadIdx.x * 32] = -1;
}

// ---- prep: pack Wcat=[Wx;Wh] into MFMA B-fragment order, bf16 ----
// B-frag mapping for mfma_f32_16x16x32_bf16: lane l holds B[k][col], col=l&15, k=kbase+(l>>4)*8+j
__global__ void k_pack_w(const float* __restrict__ Wx, const float* __restrict__ Wh,
                         u16* __restrict__ wp){
  int id = blockIdx.x * 256 + threadIdx.x;        // 262144 total
  int lane = id & 63;
  int kk = (id >> 6) & 7, n = (id >> 9) & 3, q = (id >> 11) & 3, w = id >> 13;
  int col = n * 512 + w * 16 + (lane & 15);
  int kb  = q * 256 + kk * 32 + (lane >> 4) * 8;
  union { u16 v[8]; uint4 u; } pk;
#pragma unroll
  for (int j = 0; j < 8; ++j){
    int k = kb + j;
    float f = (k < 512) ? Wx[k * 2048 + col] : Wh[(k - 512) * 2048 + col];
    pk.v[j] = f2bf(f);
  }
  long long fid = ((w * 4 + q) * 4 + n) * 8 + kk;
  *((uint4*)(wp + fid * 512) + lane) = pk.u;
}

// ---- prep: x -> per-timestep swizzled bf16 LDS images ----
__global__ void k_conv_x(const float* __restrict__ x, unsigned char* __restrict__ xs){
  int id = blockIdx.x * 256 + threadIdx.x;        // 4,194,304 total
  int g = id & 63, row = (id >> 6) & 63, t = id >> 12;
  const float* src = x + ((long long)row * TT + t) * DD + g * 8;
  union { u16 v[8]; uint4 u; } pk;
#pragma unroll
  for (int j = 0; j < 8; ++j) pk.v[j] = f2bf(src[j]);
  long long dst = (long long)t * 65536 + row * 1024 + (long long)((g ^ (row & 7)) * 16);
  *(uint4*)(xs + dst) = pk.u;
}

// ---- prep: h0 -> swizzled bf16 into hbuf[1] (read at t=0) ----
__global__ void k_conv_h0(const float* __restrict__ h0, unsigned char* __restrict__ hbuf){
  int id = blockIdx.x * 256 + threadIdx.x;        // 4096 total
  int g = id & 63, row = id >> 6;
  const float* src = h0 + row * HH + g * 8;
  union { u16 v[8]; uint4 u; } pk;
#pragma unroll
  for (int j = 0; j < 8; ++j) pk.v[j] = f2bf(src[j]);
  *(uint4*)(hbuf + 65536 + row * 1024 + (g ^ (row & 7)) * 16) = pk.u;
}

// ---- persistent scan kernel: 32 wgs x 256 threads ----
// wg w owns h-cols [16w,16w+16); its 64 a-cols = 4 gate-aligned 16-wide tiles.
// wave q = K-quarter (q<2: x half in Ax, q>=2: h half in Ah). B frags in registers.
__launch_bounds__(256, 1)
__global__ void k_lstm(const float* __restrict__ bias_g, float* __restrict__ out,
                       const u16* __restrict__ wp, const unsigned char* __restrict__ xs,
                       unsigned char* __restrict__ hbuf, int* __restrict__ flags)
{
  __shared__ __align__(16) unsigned char smem[131072];
  unsigned char* Ax = smem;
  unsigned char* Ah = smem + 65536;
  float* part = (float*)smem;   // overlay after MFMA: word off = q*4352 + col*68 + row

  const int tid  = threadIdx.x;
  const int lane = tid & 63;
  const int q    = tid >> 6;
  const int w    = blockIdx.x;

  // persistent B fragments: 4 gates x 8 k-steps = 128 VGPRs
  bf16x8 bfrag[4][8];
  {
    const bf16x8* wpf = (const bf16x8*)wp;
#pragma unroll
    for (int n = 0; n < 4; ++n)
#pragma unroll
      for (int kk = 0; kk < 8; ++kk)
        bfrag[n][kk] = wpf[(((w * 4 + q) * 4 + n) * 8 + kk) * 64 + lane];
  }

  // gate-phase mapping: thread -> (batch row, 4 consecutive h-cols)
  const int grow = tid >> 2;
  const int gjh  = (tid & 3) * 4;
  float bia[4][4];
#pragma unroll
  for (int g = 0; g < 4; ++g)
#pragma unroll
    for (int i = 0; i < 4; ++i) bia[g][i] = bias_g[g * 512 + w * 16 + gjh + i];

  float cst[4] = {0.f, 0.f, 0.f, 0.f};   // persistent cell state in registers

  const int arow = lane & 15;
  const int sxor = lane & 7;
  const int khi  = lane >> 4;
  const unsigned char* Areg = (q < 2) ? Ax : Ah;
  const int kq = q & 1;

  const int hgran_base = 2 * w + ((tid & 3) >> 1);
  const int hbyte_in   = 8 * (tid & 1);
  int* myflag = flags + w * 32;

  for (int t = 0; t < TT; ++t){
    // ---- decentralized barrier: wait until all wgs published step t-1 ----
    {
      int tgt = t - 1;
      int v;
      do {
        v = (lane < 32) ? __hip_atomic_load(flags + lane * 32, __ATOMIC_RELAXED,
                                            __HIP_MEMORY_SCOPE_AGENT)
                        : 0x7fffffff;
      } while (!__all(v >= tgt));
      __builtin_amdgcn_fence(__ATOMIC_ACQUIRE, "agent");
    }

    // ---- stage A = [x_t ; h_{t-1}] into LDS (pre-swizzled sources, linear DMA) ----
    {
      const unsigned char* xsrc = xs + (long long)t * 65536;
      const unsigned char* hsrc = hbuf + (size_t)(((unsigned)(t - 1)) & 1u) * 65536;
#pragma unroll
      for (int i = 0; i < 16; ++i){
        int off = (q * 16 + i) * 1024;
        __builtin_amdgcn_global_load_lds(
            (const __attribute__((address_space(1))) u32*)(xsrc + off + lane * 16),
            (__attribute__((address_space(3))) u32*)(Ax + off), 16, 0, 0);
        __builtin_amdgcn_global_load_lds(
            (const __attribute__((address_space(1))) u32*)(hsrc + off + lane * 16),
            (__attribute__((address_space(3))) u32*)(Ah + off), 16, 0, 0);
      }
      asm volatile("s_waitcnt vmcnt(0)" ::: "memory");
    }
    __syncthreads();

    // ---- MFMA: this wave's K-quarter, 64x64 output tile, 128 MFMAs ----
    f32x4 acc[4][4];
#pragma unroll
    for (int m = 0; m < 4; ++m)
#pragma unroll
      for (int n = 0; n < 4; ++n) acc[m][n] = (f32x4){0.f, 0.f, 0.f, 0.f};

#pragma unroll
    for (int kk = 0; kk < 8; ++kk){
      bf16x8 a[4];
      int sg = ((kq * 32 + kk * 4 + khi) ^ sxor) * 16;
#pragma unroll
      for (int m = 0; m < 4; ++m)
        a[m] = *(const bf16x8*)(Areg + (m * 16 + arow) * 1024 + sg);
#pragma unroll
      for (int m = 0; m < 4; ++m)
#pragma unroll
        for (int n = 0; n < 4; ++n)
          acc[m][n] = __builtin_amdgcn_mfma_f32_16x16x32_bf16(a[m], bfrag[n][kk],
                                                              acc[m][n], 0, 0, 0);
    }
    __syncthreads();

    // ---- K-partials to LDS (overlays Ax; [col][row] pad-68 => ~2-way banks) ----
#pragma unroll
    for (int m = 0; m < 4; ++m)
#pragma unroll
      for (int n = 0; n < 4; ++n){
        float* p = part + q * 4352 + (n * 16 + arow) * 68 + m * 16 + khi * 4;
        *(f32x4*)p = acc[m][n];
      }
    __syncthreads();

    // ---- gates: each thread 4 h-values, c in registers ----
    {
      float hv[4];
      u16 hb[4];
#pragma unroll
      for (int i = 0; i < 4; ++i){
        int colh = gjh + i;
        float ag[4];
#pragma unroll
        for (int g = 0; g < 4; ++g){
          const float* p = part + (g * 16 + colh) * 68 + grow;
          ag[g] = p[0] + p[4352] + p[2 * 4352] + p[3 * 4352] + bia[g][i];
        }
        float gi = 1.f / (1.f + __expf(-ag[0]));
        float gf = 1.f / (1.f + __expf(-ag[1]));
        float go = 1.f / (1.f + __expf(-ag[2]));
        float e2 = __expf(-2.f * fabsf(ag[3]));
        float gg = __builtin_copysignf((1.f - e2) / (1.f + e2), ag[3]);
        float c  = gf * cst[i] + gi * gg;
        cst[i] = c;
        float ec = __expf(-2.f * fabsf(c));
        float th = __builtin_copysignf((1.f - ec) / (1.f + ec), c);
        float h  = go * th;
        hv[i] = h;
        hb[i] = f2bf(h);
      }
      // hn output, coalesced float4
      float4 ov = make_float4(hv[0], hv[1], hv[2], hv[3]);
      *(float4*)(out + ((long long)grow * TT + t) * HH + w * 16 + gjh) = ov;
      // h -> swizzled bf16 double buffer for next step's A
      unsigned char* hdst = hbuf + (size_t)(t & 1) * 65536 + grow * 1024
                          + ((hgran_base ^ (grow & 7)) * 16) + hbyte_in;
      union { u16 v[4]; uint2 u; } hp;
      hp.v[0] = hb[0]; hp.v[1] = hb[1]; hp.v[2] = hb[2]; hp.v[3] = hb[3];
      *(uint2*)hdst = hp.u;
    }
    __syncthreads();
    if (tid == 0)
      __hip_atomic_store(myflag, t, __ATOMIC_RELEASE, __HIP_MEMORY_SCOPE_AGENT);
  }
}

extern "C" void kernel_launch(void* const* d_in, const int* in_sizes, int n_in,
                              void* d_out, int out_size, void* d_ws, size_t ws_size,
                              hipStream_t stream){
  const float* x  = (const float*)d_in[0];
  const float* h0 = (const float*)d_in[1];
  const float* Wx = (const float*)d_in[2];
  const float* Wh = (const float*)d_in[3];
  const float* b  = (const float*)d_in[4];
  float* out = (float*)d_out;

  unsigned char* ws = (unsigned char*)d_ws;
  u16* wp            = (u16*)(ws + OFF_WPACK);
  unsigned char* xs  = ws + OFF_XS;
  unsigned char* hb  = ws + OFF_HBUF;
  int* flags         = (int*)(ws + OFF_FLAGS);

  hipLaunchKernelGGL(k_init_flags, dim3(1),     dim3(64),  0, stream, flags);
  hipLaunchKernelGGL(k_pack_w,     dim3(1024),  dim3(256), 0, stream, Wx, Wh, wp);
  hipLaunchKernelGGL(k_conv_x,     dim3(16384), dim3(256), 0, stream, x, xs);
  hipLaunchKernelGGL(k_conv_h0,    dim3(16),    dim3(256), 0, stream, h0, hb);
  hipLaunchKernelGGL(k_lstm,       dim3(32),    dim3(256), 0, stream, b, out, wp, xs, hb, flags);
}

// Round 3
// 5219.525 us; speedup vs baseline: 1.4819x; 1.4819x over previous
//
#include <hip/hip_runtime.h>
#include <hip/hip_bf16.h>
#include <stdint.h>

#define TT 1024
#define DD 512
#define HH 512

typedef short bf16x8 __attribute__((ext_vector_type(8)));
typedef float f32x4 __attribute__((ext_vector_type(4)));
typedef unsigned long long u64;
typedef u64 u64x2 __attribute__((ext_vector_type(2)));
typedef unsigned int u32;
typedef unsigned short u16;

// ---- workspace layout (bytes) ----
#define OFF_WPACK 0ull
#define SZ_WPACK  (32ull*4*4*8*1024)       // 4 MiB B-fragments
#define OFF_XS    (OFF_WPACK + SZ_WPACK)    // 64 MiB x A-fragment blob
#define SZ_XS     (1024ull*65536)
#define OFF_HBUF  (OFF_XS + SZ_XS)          // 2 x 64 KiB h A-fragment blobs
#define SZ_HBUF   (2ull*65536)
#define OFF_FLAGS (OFF_HBUF + SZ_HBUF)      // 32 flags, 128 B apart

__device__ __forceinline__ u16 f2bf(float f){
  u32 u = __builtin_bit_cast(u32, f);
  u32 r = (u + 0x7fffu + ((u >> 16) & 1u)) >> 16;   // RNE
  return (u16)r;
}

__global__ void k_init_flags(int* flags){
  if (threadIdx.x < 32) flags[threadIdx.x * 32] = -1;
}

// ---- pack Wcat=[Wx;Wh] into B-fragment order (identical to verified r0/r1) ----
__global__ void k_pack_w(const float* __restrict__ Wx, const float* __restrict__ Wh,
                         u16* __restrict__ wp){
  int id = blockIdx.x * 256 + threadIdx.x;        // 262144
  int lane = id & 63;
  int kk = (id >> 6) & 7, n = (id >> 9) & 3, q = (id >> 11) & 3, w = id >> 13;
  int col = n * 512 + w * 16 + (lane & 15);
  int kb  = q * 256 + kk * 32 + (lane >> 4) * 8;
  union { u16 v[8]; uint4 u; } pk;
#pragma unroll
  for (int j = 0; j < 8; ++j){
    int k = kb + j;
    float f = (k < 512) ? Wx[k * 2048 + col] : Wh[(k - 512) * 2048 + col];
    pk.v[j] = f2bf(f);
  }
  long long fid = ((w * 4 + q) * 4 + n) * 8 + kk;
  *((uint4*)(wp + fid * 512) + lane) = pk.u;
}

// ---- x -> per-(t,q,kk,m,lane) A-fragment blob ----
// lane holds x[row=m*16+(lane&15)][k=q*256+kk*32+(lane>>4)*8 + j]
__global__ void k_conv_x(const float* __restrict__ x, uint4* __restrict__ xs){
  int id = blockIdx.x * 256 + threadIdx.x;        // 4,194,304
  int lane = id & 63, m = (id >> 6) & 3, kk = (id >> 8) & 7, q = (id >> 11) & 1, t = id >> 12;
  int row = m * 16 + (lane & 15);
  int k   = q * 256 + kk * 32 + (lane >> 4) * 8;
  const float* src = x + ((long long)row * TT + t) * DD + k;
  union { u16 v[8]; uint4 u; } pk;
#pragma unroll
  for (int j = 0; j < 8; ++j) pk.v[j] = f2bf(src[j]);
  xs[id] = pk.u;
}

// ---- h0 -> fragment blob, buffer 1 (read at t=0). 4096 threads EXACTLY. ----
__global__ void k_conv_h0(const float* __restrict__ h0, u16* __restrict__ hbuf){
  int id = blockIdx.x * 256 + threadIdx.x;        // 4096 total (grid 16!)
  int lane = id & 63, m = (id >> 6) & 3, kk = (id >> 8) & 7, kq = (id >> 11) & 1;
  int row = m * 16 + (lane & 15);
  int c   = kq * 256 + kk * 32 + (lane >> 4) * 8;
  const float* src = h0 + row * HH + c;
  union { u16 v[8]; uint4 u; } pk;
#pragma unroll
  for (int j = 0; j < 8; ++j) pk.v[j] = f2bf(src[j]);
  *((uint4*)(hbuf + 32768) + id) = pk.u;
}

// ---- persistent scan: 32 wgs x 256 threads ----
// wave q = K-quarter. q<2: x (independent of recurrence). q>=2: h (polls flags).
// No fences: h-blob + flag publication are agent-scope atomic SWAPs (execute at
// coherence point); producer ordering = swaps -> s_waitcnt vmcnt(0) -> barrier
// -> flag swap. Consumers: relaxed atomic poll + relaxed atomic h loads.
__launch_bounds__(256, 1)
__global__ void k_lstm(const float* __restrict__ bias_g, float* __restrict__ out,
                       const u16* __restrict__ wp, const uint4* __restrict__ xs,
                       u16* __restrict__ hbuf, int* __restrict__ flags)
{
  __shared__ float part[4 * 4160];   // [q][row(64)][col(64)] stride 65

  const int tid  = threadIdx.x;
  const int lane = tid & 63;
  const int q    = tid >> 6;
  const int w    = blockIdx.x;
  const int khi  = lane >> 4;
  const int llo  = lane & 15;

  // persistent B fragments: 128 VGPRs
  bf16x8 bfrag[4][8];
  {
    const bf16x8* wpf = (const bf16x8*)wp;
#pragma unroll
    for (int n = 0; n < 4; ++n)
#pragma unroll
      for (int kk = 0; kk < 8; ++kk)
        bfrag[n][kk] = wpf[(((w * 4 + q) * 4 + n) * 8 + kk) * 64 + lane];
  }

  // gate-phase mapping: thread -> (batch row, 4 consecutive h-cols)
  const int grow = tid >> 2;
  const int gjh  = (tid & 3) * 4;
  float bia[4][4];
#pragma unroll
  for (int g = 0; g < 4; ++g)
#pragma unroll
    for (int i = 0; i < 4; ++i) bia[g][i] = bias_g[g * 512 + w * 16 + gjh + i];

  float cst[4] = {0.f, 0.f, 0.f, 0.f};

  // h-store position in fragment blob (u16 units), derived from (grow, c0=w*16+gjh)
  const int s_kq = w >> 4;
  const int s_kk = (w >> 1) & 7;
  const int s_hi = ((w & 1) * 2 + ((tid & 3) >> 1)) & 3;
  const int s_elem = ((((s_kq * 8 + s_kk) * 4 + (grow >> 4)) * 64
                       + s_hi * 16 + (grow & 15)) * 8) + (tid & 1) * 4;

  const bool is_h = (q >= 2);
  const int  kq   = q & 1;
  int* myflag = flags + w * 32;

  for (int t = 0; t < TT; ++t){
    f32x4 acc[4][4];
#pragma unroll
    for (int m = 0; m < 4; ++m)
#pragma unroll
      for (int n = 0; n < 4; ++n) acc[m][n] = (f32x4){0.f, 0.f, 0.f, 0.f};

    bf16x8 afrag[8][4];

    if (!is_h){
      // x fragments: plain cached loads (L2 stays warm; nothing invalidates it)
      const uint4* base = xs + (((long long)(t * 2 + q) * 8) * 4) * 64 + lane;
#pragma unroll
      for (int kk = 0; kk < 8; ++kk)
#pragma unroll
        for (int m = 0; m < 4; ++m)
          afrag[kk][m] = __builtin_bit_cast(bf16x8, base[(kk * 4 + m) * 64]);
    } else {
      // wait for all wgs to have published h_{t-1}
      {
        int tgt = t - 1, v;
        do {
          v = (lane < 32) ? __hip_atomic_load(flags + lane * 32, __ATOMIC_RELAXED,
                                              __HIP_MEMORY_SCOPE_AGENT)
                          : 0x7fffffff;
        } while (!__all(v >= tgt));
        asm volatile("" ::: "memory");
      }
      // h fragments: agent-coherent u64 loads from fragment blob
      const u64* hb = (const u64*)(hbuf + (size_t)(((unsigned)(t - 1)) & 1u) * 32768);
#pragma unroll
      for (int kk = 0; kk < 8; ++kk)
#pragma unroll
        for (int m = 0; m < 4; ++m){
          int fi = (((kq * 8 + kk) * 4 + m) * 64 + lane) * 2;
          u64x2 r;
          r.x = __hip_atomic_load((u64*)(hb + fi),     __ATOMIC_RELAXED, __HIP_MEMORY_SCOPE_AGENT);
          r.y = __hip_atomic_load((u64*)(hb + fi + 1), __ATOMIC_RELAXED, __HIP_MEMORY_SCOPE_AGENT);
          afrag[kk][m] = __builtin_bit_cast(bf16x8, r);
        }
    }

#pragma unroll
    for (int kk = 0; kk < 8; ++kk)
#pragma unroll
      for (int m = 0; m < 4; ++m)
#pragma unroll
        for (int n = 0; n < 4; ++n)
          acc[m][n] = __builtin_amdgcn_mfma_f32_16x16x32_bf16(afrag[kk][m], bfrag[n][kk],
                                                              acc[m][n], 0, 0, 0);

    // K-partials to LDS: part[q][row][col], stride 65 (<=2-way banks on writes)
#pragma unroll
    for (int m = 0; m < 4; ++m)
#pragma unroll
      for (int n = 0; n < 4; ++n)
#pragma unroll
        for (int r = 0; r < 4; ++r)
          part[q * 4160 + (m * 16 + khi * 4 + r) * 65 + n * 16 + llo] = acc[m][n][r];
    __syncthreads();

    // gates: each thread 4 h-values, c in registers
    {
      float hv[4]; u16 hb16[4];
#pragma unroll
      for (int i = 0; i < 4; ++i){
        int col = gjh + i;
        float ag[4];
#pragma unroll
        for (int g = 0; g < 4; ++g){
          const float* p = part + grow * 65 + g * 16 + col;
          ag[g] = p[0] + p[4160] + p[2 * 4160] + p[3 * 4160] + bia[g][i];
        }
        float gi = 1.f / (1.f + __expf(-ag[0]));
        float gf = 1.f / (1.f + __expf(-ag[1]));
        float go = 1.f / (1.f + __expf(-ag[2]));
        float e2 = __expf(-2.f * fabsf(ag[3]));
        float gg = __builtin_copysignf((1.f - e2) / (1.f + e2), ag[3]);
        float c  = gf * cst[i] + gi * gg;
        cst[i] = c;
        float ec = __expf(-2.f * fabsf(c));
        float th = __builtin_copysignf((1.f - ec) / (1.f + ec), c);
        hv[i] = go * th;
        hb16[i] = f2bf(hv[i]);
      }
      float4 ov = make_float4(hv[0], hv[1], hv[2], hv[3]);
      *(float4*)(out + ((long long)grow * TT + t) * HH + w * 16 + gjh) = ov;

      // h -> fragment blob via atomic swap (executes at agent coherence point)
      u64 hword = (u64)hb16[0] | ((u64)hb16[1] << 16) | ((u64)hb16[2] << 32) | ((u64)hb16[3] << 48);
      (void)__hip_atomic_exchange((u64*)(hbuf + (size_t)(t & 1) * 32768 + s_elem), hword,
                                  __ATOMIC_RELAXED, __HIP_MEMORY_SCOPE_AGENT);
    }
    asm volatile("s_waitcnt vmcnt(0)" ::: "memory");  // h swaps ack'd at coherence point
    __syncthreads();                                   // all waves' swaps ack'd
    if (tid == 0)
      (void)__hip_atomic_exchange(myflag, t, __ATOMIC_RELAXED, __HIP_MEMORY_SCOPE_AGENT);
  }
}

extern "C" void kernel_launch(void* const* d_in, const int* in_sizes, int n_in,
                              void* d_out, int out_size, void* d_ws, size_t ws_size,
                              hipStream_t stream){
  const float* x  = (const float*)d_in[0];
  const float* h0 = (const float*)d_in[1];
  const float* Wx = (const float*)d_in[2];
  const float* Wh = (const float*)d_in[3];
  const float* b  = (const float*)d_in[4];
  float* out = (float*)d_out;

  unsigned char* ws = (unsigned char*)d_ws;
  u16*  wp    = (u16*)(ws + OFF_WPACK);
  uint4* xs   = (uint4*)(ws + OFF_XS);
  u16*  hb    = (u16*)(ws + OFF_HBUF);
  int*  flags = (int*)(ws + OFF_FLAGS);

  hipLaunchKernelGGL(k_init_flags, dim3(1),     dim3(64),  0, stream, flags);
  hipLaunchKernelGGL(k_pack_w,     dim3(1024),  dim3(256), 0, stream, Wx, Wh, wp);
  hipLaunchKernelGGL(k_conv_x,     dim3(16384), dim3(256), 0, stream, x, xs);
  hipLaunchKernelGGL(k_conv_h0,    dim3(16),    dim3(256), 0, stream, h0, hb);
  hipLaunchKernelGGL(k_lstm,       dim3(32),    dim3(256), 0, stream, b, out, wp, xs, hb, flags);
}